// Round 3
// baseline (374.146 us; speedup 1.0000x reference)
//
#include <hip/hip_runtime.h>

// Problem constants
static constexpr int BB = 4;
static constexpr int SS = 4096;
static constexpr int DD = 1024;
static constexpr int HH = 8;
static constexpr int HD = 128;     // FFT length
static constexpr int CS = 32;      // scan chunk size (positions per block)
static constexpr int NCHUNK = SS / CS;   // 128
static constexpr int MROWS = BB * SS;    // 16384

typedef __attribute__((ext_vector_type(8))) short bfrag;    // 8 bf16 (4 VGPRs)
typedef __attribute__((ext_vector_type(4))) float floatx4;  // MFMA acc

// ---------------------------------------------------------------------------
// bf16 helpers
// ---------------------------------------------------------------------------
__device__ __forceinline__ float bf2f(unsigned int u) {   // low 16 bits = bf16
    return __uint_as_float((u & 0xFFFFu) << 16);
}
__device__ __forceinline__ unsigned short f2bf(float f) {  // RNE
    unsigned int x = __float_as_uint(f);
    unsigned int r = x + 0x7FFFu + ((x >> 16) & 1u);
    return (unsigned short)(r >> 16);
}
__device__ __forceinline__ unsigned int pack_rne(float a, float b) {
    return ((unsigned int)f2bf(a)) | (((unsigned int)f2bf(b)) << 16);
}

// async global->LDS, 16B per lane; LDS dest = wave-uniform base + lane*16
__device__ __forceinline__ void async_copy16(const void* g, void* l) {
    __builtin_amdgcn_global_load_lds(
        (const __attribute__((address_space(1))) unsigned int*)g,
        (__attribute__((address_space(3))) unsigned int*)l, 16, 0, 0);
}

// ---------------------------------------------------------------------------
// Complex helpers
// ---------------------------------------------------------------------------
struct cpx { float re, im; };

__device__ __forceinline__ cpx cadd(cpx a, cpx b) { return {a.re + b.re, a.im + b.im}; }
__device__ __forceinline__ cpx csub(cpx a, cpx b) { return {a.re - b.re, a.im - b.im}; }
__device__ __forceinline__ cpx cmul(cpx a, cpx b) {
    return { fmaf(a.re, b.re, -a.im * b.im), fmaf(a.re, b.im, a.im * b.re) };
}
__device__ __forceinline__ cpx cmul_cj(cpx a, cpx b) {   // a * conj(b)
    return { fmaf(a.re, b.re, a.im * b.im), fmaf(a.im, b.re, -a.re * b.im) };
}
__device__ __forceinline__ cpx shflx(cpx x, int m) {
    return { __shfl_xor(x.re, m), __shfl_xor(x.im, m) };
}
__device__ __forceinline__ cpx shfl_at(cpx x, int src) {
    return { __shfl(x.re, src), __shfl(x.im, src) };
}

__device__ __forceinline__ int pair_lane_even(int l) {
    int m = (int)(__brev((unsigned)l) >> 26);
    int mp = (64 - m) & 63;
    return (int)(__brev((unsigned)mp) >> 26);
}

__device__ __forceinline__ void make_tw(int lane, cpx tw[7]) {
    const float NEG2PI = -6.28318530717958647692f;
    float a0 = NEG2PI * (float)lane * (1.0f / 128.0f);
    tw[0] = { __cosf(a0), __sinf(a0) };
    int d = 32;
#pragma unroll
    for (int s = 1; s <= 6; ++s) {
        int i = lane & (d - 1);
        float a = NEG2PI * (float)i / (float)(2 * d);
        tw[s] = { __cosf(a), __sinf(a) };
        d >>= 1;
    }
}

// Forward DIF FFT-128 (complex): natural in, bit-reversed out. Unnormalized.
__device__ __forceinline__ void fft128_fwd(cpx& x0, cpx& x1, const cpx tw[7], int lane) {
    cpx a = x0, b = x1;
    x0 = cadd(a, b);
    x1 = cmul(csub(a, b), tw[0]);
    int d = 32;
#pragma unroll
    for (int s = 1; s <= 6; ++s) {
        const bool up = (lane & d) != 0;
        cpx o0 = shflx(x0, d);
        cpx o1 = shflx(x1, d);
        cpx s0 = cadd(x0, o0);
        cpx s1 = cadd(x1, o1);
        cpx d0 = cmul(csub(o0, x0), tw[s]);
        cpx d1 = cmul(csub(o1, x1), tw[s]);
        x0 = up ? d0 : s0;
        x1 = up ? d1 : s1;
        d >>= 1;
    }
}

// Inverse DIT FFT-128: consumes fwd's permuted order, natural order out, /128.
__device__ __forceinline__ void fft128_inv(cpx& x0, cpx& x1, const cpx tw[7], int lane) {
    int d = 1;
#pragma unroll
    for (int s = 6; s >= 1; --s) {
        const bool up = (lane & d) != 0;
        cpx o0 = shflx(x0, d);
        cpx o1 = shflx(x1, d);
        cpx b0 = up ? x0 : o0;
        cpx a0 = up ? o0 : x0;
        cpx b1 = up ? x1 : o1;
        cpx a1 = up ? o1 : x1;
        cpx t0 = cmul_cj(b0, tw[s]);
        cpx t1 = cmul_cj(b1, tw[s]);
        x0 = up ? csub(a0, t0) : cadd(a0, t0);
        x1 = up ? csub(a1, t1) : cadd(a1, t1);
        d <<= 1;
    }
    cpx t = cmul_cj(x1, tw[0]);
    cpx a = x0;
    const float inv = 0.0078125f;
    x0 = { (a.re + t.re) * inv, (a.im + t.im) * inv };
    x1 = { (a.re - t.re) * inv, (a.im - t.im) * inv };
}

// ---------------------------------------------------------------------------
// x fp32 -> bf16 (RNE), 8 elems/thread
// ---------------------------------------------------------------------------
__global__ __launch_bounds__(256) void convert_bf16(const float* __restrict__ X,
                                                    unsigned short* __restrict__ Y)
{
    const size_t i = ((size_t)blockIdx.x * 256 + threadIdx.x) * 8;
    float4 v0 = *reinterpret_cast<const float4*>(X + i);
    float4 v1 = *reinterpret_cast<const float4*>(X + i + 4);
    uint4 p = { pack_rne(v0.x, v0.y), pack_rne(v0.z, v0.w),
                pack_rne(v1.x, v1.y), pack_rne(v1.z, v1.w) };
    *reinterpret_cast<uint4*>(Y + i) = p;
}

// Transpose + RNE bf16: W fp32 [K,N] -> T bf16 [N,K]
__global__ __launch_bounds__(256) void transpose_rn(const float* __restrict__ W,
                                                    unsigned short* __restrict__ T,
                                                    int K, int N)
{
    __shared__ float tile[32][33];
    const int n0 = blockIdx.x * 32, k0 = blockIdx.y * 32;
    const int r = threadIdx.x >> 5, c = threadIdx.x & 31;
#pragma unroll
    for (int i = 0; i < 4; ++i)
        tile[r + 8 * i][c] = W[(size_t)(k0 + r + 8 * i) * N + n0 + c];
    __syncthreads();
#pragma unroll
    for (int i = 0; i < 4; ++i) {
        float v = tile[c][r + 8 * i];
        T[(size_t)(n0 + r + 8 * i) * K + k0 + c] = f2bf(v);
    }
}

// ---------------------------------------------------------------------------
// 256x256-tile bf16 GEMM, BK=64, 4 phases/iter, READ-AHEAD pipeline:
// each phase issues the NEXT phase's ds_reads before its own MFMA cluster,
// so the LDS-port drain overlaps the matrix pipe (the R2 structure serialized
// them -> 38% MfmaUtil).  ONE barrier per phase.  Counted vmcnt (never 0 in
// steady state).  C[M,N] = A[M,K](bf16) * Bt[N,K]^T(bf16).
//
// LDS 128 KiB = 2 bufs x { A[kk][256][32] | B[kk][256][32] } (4x16KB halves).
//
// Phase map (iter j):         MFMA              reads (for next phase)   stage
//   P0: aflo0 x bf0 -> acc[0..3]   afhi0 (4)                A1(j+1)
//   P1: afhi0 x bf0 -> acc[4..7]   bf1+aflo1 (8)            B1(j+1)
//   P2: aflo1 x bf1 -> acc[0..3]   afhi1 (4)                A0(j+2)
//   P3: afhi1 x bf1 -> acc[4..7]   bf0',aflo0' (8, next bb) B0(j+2)
// vmcnt(6) after each stage (stage@t lands by end of t+3, published by that
// phase's end barrier; all first-reads occur >= 1 phase after publish).
// Slot-free proof: a slot staged at phase s was last READ >=2 phases before s
// and those reads complete before their consuming MFMA (compiler lgkm wait),
// i.e. before the barrier ending that phase.  Tail: vmcnt(4) at P2(NT-2),
// vmcnt(0) at P0(NT-1).
//
// Swizzle (both-sides, rule #21): LDS 16B-slot s of row r holds global slot
// s ^ ((r>>1)&3); applied by pre-swizzling the per-lane GLOBAL source (LDS
// dest stays linear for global_load_lds) and XOR-ing the ds_read address.
// ---------------------------------------------------------------------------
template <typename OutT>
__global__ __launch_bounds__(512, 2) void gemm256(const unsigned short* __restrict__ A,
                                                  const unsigned short* __restrict__ Bt,
                                                  OutT* __restrict__ C,
                                                  int M, int N, int K)
{
    extern __shared__ __align__(16) unsigned short lds[];

    const int tid = threadIdx.x, lane = tid & 63, w = tid >> 6;
    const int wr = w >> 2, wc = w & 3;   // 2 x 4 wave grid, per-wave out 128x64

    // T1: XCD-aware bijective swizzle (gridDim.x % 8 == 0 here)
    const int nbx = N >> 8;
    const int cpx_ = gridDim.x >> 3;
    const int wg = blockIdx.x;
    const int swz = (wg & 7) * cpx_ + (wg >> 3);
    const int n0 = (swz % nbx) << 8;
    const int m0 = (swz / nbx) << 8;

    // --- staging (per-lane global source carries the inverse swizzle) ---
    const int lr = lane >> 2;                                  // row within 16-row chunk
    const int kx = (((lane & 3) ^ ((lane >> 3) & 3)) << 3);    // swizzled k-elem offset
    const unsigned short* gA = A  + (size_t)(m0 + 32 * w + lr) * K + kx;
    const unsigned short* gB = Bt + (size_t)(n0 + 32 * w + lr) * K + kx;

    auto stageA = [&](int buf, int kk, int kelem) {
        unsigned short* dst = lds + buf * 32768 + kk * 8192 + (32 * w) * 32;
        const unsigned short* src = gA + kelem;
        async_copy16(src, dst);
        async_copy16(src + (size_t)16 * K, dst + 512);
    };
    auto stageB = [&](int buf, int kk, int kelem) {
        unsigned short* dst = lds + buf * 32768 + 16384 + kk * 8192 + (32 * w) * 32;
        const unsigned short* src = gB + kelem;
        async_copy16(src, dst);
        async_copy16(src + (size_t)16 * K, dst + 512);
    };

    // --- fragment read bases (ushort units) ---
    const int sl = lane >> 4;                        // global 16B k-slot wanted
    const int xa = ((lane & 15) >> 1) & 3;           // row-derived XOR
    const int soff = ((sl ^ xa) << 3);
    const int ra = (wr * 128 + (lane & 15)) * 32 + soff;   // + m*512
    const int rb = (wc * 64  + (lane & 15)) * 32 + soff;   // + n*512

    floatx4 acc[8][4];
#pragma unroll
    for (int m = 0; m < 8; ++m)
#pragma unroll
        for (int n = 0; n < 4; ++n) { floatx4 z = {0.f, 0.f, 0.f, 0.f}; acc[m][n] = z; }

    const int NT = K >> 6;   // BK = 64 per iter (NT = 16 here)

    // prologue: iter0 all 4 halves + iter1 kk0 pair
    stageA(0, 0, 0);  stageB(0, 0, 0);
    stageA(0, 1, 32); stageB(0, 1, 32);
    if (NT > 1) { stageA(1, 0, 64); stageB(1, 0, 64); }
    asm volatile("s_waitcnt vmcnt(8)" ::: "memory");   // A0(0), B0(0) landed
    __builtin_amdgcn_s_barrier();
    __builtin_amdgcn_sched_barrier(0);

    // initial fragments for P0(0)
    bfrag bf0[4], aflo0[4];
#pragma unroll
    for (int m = 0; m < 4; ++m)
        aflo0[m] = *reinterpret_cast<const bfrag*>(lds + ra + m * 512);
#pragma unroll
    for (int n = 0; n < 4; ++n)
        bf0[n] = *reinterpret_cast<const bfrag*>(lds + 16384 + rb + n * 512);

    for (int j = 0; j < NT; ++j) {
        const int bb = (j & 1) * 32768;
        const int nb = ((j + 1) & 1) * 32768;
        bfrag afhi0[4], bf1[4], aflo1[4], afhi1[4], bf0n[4], aflo0n[4];

        // ---------------- P0: MFMA aflo0 x bf0 ; read afhi0 ; stage A1(j+1)
        if (j + 1 < NT) stageA((j + 1) & 1, 1, (j + 1) * 64 + 32);
#pragma unroll
        for (int m = 0; m < 4; ++m)
            afhi0[m] = *reinterpret_cast<const bfrag*>(lds + bb + ra + 2048 + m * 512);
        if (j + 1 < NT) asm volatile("s_waitcnt vmcnt(6)" ::: "memory");
        else            asm volatile("s_waitcnt vmcnt(0)" ::: "memory");
        __builtin_amdgcn_sched_barrier(0);
        __builtin_amdgcn_s_setprio(1);
#pragma unroll
        for (int m = 0; m < 4; ++m)
#pragma unroll
            for (int n = 0; n < 4; ++n)
                acc[m][n] = __builtin_amdgcn_mfma_f32_16x16x32_bf16(aflo0[m], bf0[n], acc[m][n], 0, 0, 0);
        __builtin_amdgcn_s_setprio(0);
        __builtin_amdgcn_s_barrier();
        __builtin_amdgcn_sched_barrier(0);

        // ---------------- P1: MFMA afhi0 x bf0 ; read bf1+aflo1 ; stage B1(j+1)
        if (j + 1 < NT) stageB((j + 1) & 1, 1, (j + 1) * 64 + 32);
#pragma unroll
        for (int m = 0; m < 4; ++m)
            aflo1[m] = *reinterpret_cast<const bfrag*>(lds + bb + 8192 + ra + m * 512);
#pragma unroll
        for (int n = 0; n < 4; ++n)
            bf1[n] = *reinterpret_cast<const bfrag*>(lds + bb + 16384 + 8192 + rb + n * 512);
        asm volatile("s_waitcnt vmcnt(6)" ::: "memory");
        __builtin_amdgcn_sched_barrier(0);
        __builtin_amdgcn_s_setprio(1);
#pragma unroll
        for (int m = 0; m < 4; ++m)
#pragma unroll
            for (int n = 0; n < 4; ++n)
                acc[4 + m][n] = __builtin_amdgcn_mfma_f32_16x16x32_bf16(afhi0[m], bf0[n], acc[4 + m][n], 0, 0, 0);
        __builtin_amdgcn_s_setprio(0);
        __builtin_amdgcn_s_barrier();
        __builtin_amdgcn_sched_barrier(0);

        // ---------------- P2: MFMA aflo1 x bf1 ; read afhi1 ; stage A0(j+2)
        if (j + 2 < NT) stageA(j & 1, 0, (j + 2) * 64);
#pragma unroll
        for (int m = 0; m < 4; ++m)
            afhi1[m] = *reinterpret_cast<const bfrag*>(lds + bb + 8192 + ra + 2048 + m * 512);
        if (j + 2 < NT)      asm volatile("s_waitcnt vmcnt(6)" ::: "memory");
        else if (j + 1 < NT) asm volatile("s_waitcnt vmcnt(4)" ::: "memory");
        __builtin_amdgcn_sched_barrier(0);
        __builtin_amdgcn_s_setprio(1);
#pragma unroll
        for (int m = 0; m < 4; ++m)
#pragma unroll
            for (int n = 0; n < 4; ++n)
                acc[m][n] = __builtin_amdgcn_mfma_f32_16x16x32_bf16(aflo1[m], bf1[n], acc[m][n], 0, 0, 0);
        __builtin_amdgcn_s_setprio(0);
        __builtin_amdgcn_s_barrier();
        __builtin_amdgcn_sched_barrier(0);

        // ---------------- P3: MFMA afhi1 x bf1 ; read next bf0/aflo0 ; stage B0(j+2)
        if (j + 2 < NT) stageB(j & 1, 0, (j + 2) * 64);
        if (j + 1 < NT) {
#pragma unroll
            for (int m = 0; m < 4; ++m)
                aflo0n[m] = *reinterpret_cast<const bfrag*>(lds + nb + ra + m * 512);
#pragma unroll
            for (int n = 0; n < 4; ++n)
                bf0n[n] = *reinterpret_cast<const bfrag*>(lds + nb + 16384 + rb + n * 512);
        }
        if (j + 2 < NT) asm volatile("s_waitcnt vmcnt(6)" ::: "memory");
        __builtin_amdgcn_sched_barrier(0);
        __builtin_amdgcn_s_setprio(1);
#pragma unroll
        for (int m = 0; m < 4; ++m)
#pragma unroll
            for (int n = 0; n < 4; ++n)
                acc[4 + m][n] = __builtin_amdgcn_mfma_f32_16x16x32_bf16(afhi1[m], bf1[n], acc[4 + m][n], 0, 0, 0);
        __builtin_amdgcn_s_setprio(0);
        __builtin_amdgcn_s_barrier();
        __builtin_amdgcn_sched_barrier(0);

        if (j + 1 < NT) {
#pragma unroll
            for (int m = 0; m < 4; ++m) aflo0[m] = aflo0n[m];
#pragma unroll
            for (int n = 0; n < 4; ++n) bf0[n] = bf0n[n];
        }
    }

    // ---- epilogue ----
    if constexpr (sizeof(OutT) == 2) {
        // repack through LDS (all waves past final barrier): wave-private
        // 128x64 bf16 tile, then 16B/lane coalesced stores.
        unsigned short* myt = lds + w * 8192;
#pragma unroll
        for (int m = 0; m < 8; ++m)
#pragma unroll
            for (int n = 0; n < 4; ++n)
#pragma unroll
                for (int r = 0; r < 4; ++r)
                    myt[(m * 16 + sl * 4 + r) * 64 + n * 16 + (lane & 15)] = f2bf(acc[m][n][r]);
        asm volatile("s_waitcnt lgkmcnt(0)" ::: "memory");
#pragma unroll
        for (int c = 0; c < 16; ++c) {
            const int idx = c * 64 + lane;
            const int row = idx >> 3, cc = (idx & 7) << 3;
            uint4 v = *reinterpret_cast<const uint4*>(myt + idx * 8);
            *reinterpret_cast<uint4*>(C + (size_t)(m0 + wr * 128 + row) * N + (n0 + wc * 64 + cc)) = v;
        }
    } else {
#pragma unroll
        for (int m = 0; m < 8; ++m)
#pragma unroll
            for (int n = 0; n < 4; ++n)
#pragma unroll
                for (int r = 0; r < 4; ++r) {
                    const int row = m0 + wr * 128 + m * 16 + sl * 4 + r;
                    const int col = n0 + wc * 64 + n * 16 + (lane & 15);
                    C[(size_t)row * N + col] = acc[m][n][r];
                }
    }
}

// ---------------------------------------------------------------------------
// Phase A: one packed FFT Z=FFT(k+iv) per position; P = FK*FV via conjugate
// pairing. Stores P (bf16 packed, permuted array-position order) and
// per-chunk totals (fp32).
// ---------------------------------------------------------------------------
__global__ __launch_bounds__(256) void hrr_phaseA(const unsigned short* __restrict__ qkv,
                                                  unsigned int* __restrict__ P,
                                                  float* __restrict__ totals)
{
    const int blk = blockIdx.x;
    const int bh = blk / NCHUNK;
    const int chunk = blk % NCHUNK;
    const int b = bh >> 3, h = bh & 7;
    const int tid = threadIdx.x;
    const int wave = tid >> 6, lane = tid & 63;

    cpx tw[7];
    make_tw(lane, tw);
    const int pl0 = pair_lane_even(lane);
    const int pl1 = lane ^ 63;

    cpx acc0 = {0.f, 0.f}, acc1 = {0.f, 0.f};
    const int s0 = chunk * CS + wave * (CS / 4);
    for (int i = 0; i < CS / 4; ++i) {
        const int s = s0 + i;
        const unsigned short* base = qkv + (size_t)(b * SS + s) * 3072 + h * 128;
        cpx z0 = { bf2f(base[1024 + lane]),      bf2f(base[2048 + lane]) };
        cpx z1 = { bf2f(base[1024 + 64 + lane]), bf2f(base[2048 + 64 + lane]) };
        fft128_fwd(z0, z1, tw, lane);
        cpx sq0 = cmul(z0, z0);
        cpx sq1 = cmul(z1, z1);
        cpx sp0 = shfl_at(sq0, pl0);
        cpx sp1 = shfl_at(sq1, pl1);
        cpx p0 = { 0.25f * (sq0.im + sp0.im), 0.25f * (sp0.re - sq0.re) };
        cpx p1 = { 0.25f * (sq1.im + sp1.im), 0.25f * (sp1.re - sq1.re) };
        acc0 = cadd(acc0, p0);
        acc1 = cadd(acc1, p1);
        unsigned int* prow = P + ((size_t)bh * SS + s) * 128;
        prow[lane]      = pack_rne(p0.re, p0.im);
        prow[64 + lane] = pack_rne(p1.re, p1.im);
    }

    __shared__ float red[4][256];
    red[wave][lane * 2 + 0] = acc0.re;
    red[wave][lane * 2 + 1] = acc0.im;
    red[wave][128 + lane * 2 + 0] = acc1.re;
    red[wave][128 + lane * 2 + 1] = acc1.im;
    __syncthreads();

    float s4 = red[0][tid] + red[1][tid] + red[2][tid] + red[3][tid];
    totals[((size_t)bh * NCHUNK + chunk) * 256 + tid] = s4;
}

// ---------------------------------------------------------------------------
// Phase B: exclusive scan of chunk totals over 128 chunks per (bh, comp)
// ---------------------------------------------------------------------------
__global__ __launch_bounds__(256) void hrr_phaseB(float* __restrict__ totals)
{
    const int bh = blockIdx.x;
    const int t = threadIdx.x;
    float run = 0.f;
#pragma unroll 4
    for (int c = 0; c < NCHUNK; ++c) {
        const size_t idx = ((size_t)bh * NCHUNK + c) * 256 + t;
        float v = totals[idx];
        totals[idx] = run;
        run += v;
    }
}

// ---------------------------------------------------------------------------
// Phase C: load P (bf16) -> fp32 LDS, in-chunk scan, then paired unbind + IFFT
// ---------------------------------------------------------------------------
__global__ __launch_bounds__(256) void hrr_phaseC(const unsigned short* __restrict__ qkv,
                                                  const unsigned int* __restrict__ P,
                                                  const float* __restrict__ totals,
                                                  unsigned short* __restrict__ vals)
{
    __shared__ float Pf[CS * 256];   // 32 KB

    const int blk = blockIdx.x;
    const int bh = blk / NCHUNK;
    const int chunk = blk % NCHUNK;
    const int b = bh >> 3, h = bh & 7;
    const int tid = threadIdx.x;
    const int wave = tid >> 6, lane = tid & 63;

    cpx tw[7];
    make_tw(lane, tw);
    const int pl0 = pair_lane_even(lane);
    const int pl1 = lane ^ 63;

#pragma unroll
    for (int it = 0; it < CS / 4; ++it) {
        const int sl = it * 4 + wave;
        const int s = chunk * CS + sl;
        const unsigned int* prow = P + ((size_t)bh * SS + s) * 128;
        unsigned int a = prow[lane];
        unsigned int c = prow[64 + lane];
        float2 fa = { bf2f(a), bf2f(a >> 16) };
        float2 fc = { bf2f(c), bf2f(c >> 16) };
        *reinterpret_cast<float2*>(&Pf[sl * 256 + 2 * lane]) = fa;
        *reinterpret_cast<float2*>(&Pf[sl * 256 + 128 + 2 * lane]) = fc;
    }
    __syncthreads();

    {
        float run = totals[((size_t)bh * NCHUNK + chunk) * 256 + tid];
#pragma unroll 8
        for (int s = 0; s < CS; ++s) {
            run += Pf[s * 256 + tid];
            Pf[s * 256 + tid] = run;
        }
    }
    __syncthreads();

    for (int i = 0; i < CS / 8; ++i) {
        const int sl = wave * (CS / 4) + 2 * i;
        const int s1 = chunk * CS + sl;
        const unsigned short* b1 = qkv + (size_t)(b * SS + s1) * 3072 + h * 128;
        const unsigned short* b2 = b1 + 3072;
        cpx z0 = { bf2f(b1[lane]),      bf2f(b2[lane]) };
        cpx z1 = { bf2f(b1[64 + lane]), bf2f(b2[64 + lane]) };
        fft128_fwd(z0, z1, tw, lane);
        cpx B0 = shfl_at(z0, pl0);
        cpx B1 = shfl_at(z1, pl1);
        cpx cf1_0 = { 0.5f * (z0.re + B0.re), 0.5f * (B0.im - z0.im) };
        cpx cf1_1 = { 0.5f * (z1.re + B1.re), 0.5f * (B1.im - z1.im) };
        cpx cf2_0 = { 0.5f * (z0.im + B0.im), 0.5f * (z0.re - B0.re) };
        cpx cf2_1 = { 0.5f * (z1.im + B1.im), 0.5f * (z1.re - B1.re) };

        const float* r1 = &Pf[sl * 256];
        const float* r2 = r1 + 256;
        float2 t0 = *reinterpret_cast<const float2*>(&r1[2 * lane]);
        float2 t1 = *reinterpret_cast<const float2*>(&r1[128 + 2 * lane]);
        float2 t2 = *reinterpret_cast<const float2*>(&r2[2 * lane]);
        float2 t3 = *reinterpret_cast<const float2*>(&r2[128 + 2 * lane]);
        cpx C1_0 = { t0.x, t0.y }, C1_1 = { t1.x, t1.y };
        cpx C2_0 = { t2.x, t2.y }, C2_1 = { t3.x, t3.y };

        cpx a0 = cmul(C1_0, cf1_0), w0 = cmul(C2_0, cf2_0);
        cpx a1 = cmul(C1_1, cf1_1), w1 = cmul(C2_1, cf2_1);
        cpx u0 = { a0.re - w0.im, a0.im + w0.re };
        cpx u1 = { a1.re - w1.im, a1.im + w1.re };
        fft128_inv(u0, u1, tw, lane);

        unsigned short* o1 = vals + (size_t)(b * SS + s1) * DD + h * 128;
        unsigned short* o2 = o1 + DD;
        o1[lane]      = f2bf(u0.re);
        o1[64 + lane] = f2bf(u1.re);
        o2[lane]      = f2bf(u0.im);
        o2[64 + lane] = f2bf(u1.im);
    }
}

// ---------------------------------------------------------------------------
// Launch
// ---------------------------------------------------------------------------
extern "C" void kernel_launch(void* const* d_in, const int* in_sizes, int n_in,
                              void* d_out, int out_size, void* d_ws, size_t ws_size,
                              hipStream_t stream) {
    const float* x     = (const float*)d_in[0];   // [B,S,D]
    const float* w_qkv = (const float*)d_in[1];   // [D, 3D]
    const float* w_out = (const float*)d_in[2];   // [D, D]
    float* out = (float*)d_out;                   // [B,S,D]

    unsigned short* qkv  = (unsigned short*)d_ws;
    unsigned short* xb   = qkv + (size_t)MROWS * 3072;
    unsigned short* vals = xb + (size_t)MROWS * DD;
    unsigned int* P      = (unsigned int*)(vals + (size_t)MROWS * DD);
    float* totals        = (float*)(P + (size_t)32 * SS * 128);
    unsigned short* wqkvt = (unsigned short*)(totals + (size_t)32 * NCHUNK * 256);
    unsigned short* woutt = wqkvt + (size_t)3072 * 1024;

    // allow 128 KiB dynamic LDS (idempotent; not a stream op)
    static bool attr_done = false;
    if (!attr_done) {
        hipFuncSetAttribute(reinterpret_cast<const void*>(gemm256<unsigned short>),
                            hipFuncAttributeMaxDynamicSharedMemorySize, 131072);
        hipFuncSetAttribute(reinterpret_cast<const void*>(gemm256<float>),
                            hipFuncAttributeMaxDynamicSharedMemorySize, 131072);
        attr_done = true;
    }

    // 0) input prep
    convert_bf16<<<(MROWS * DD) / (256 * 8), 256, 0, stream>>>(x, xb);
    transpose_rn<<<dim3(3072 / 32, 1024 / 32), 256, 0, stream>>>(w_qkv, wqkvt, 1024, 3072);
    transpose_rn<<<dim3(1024 / 32, 1024 / 32), 256, 0, stream>>>(w_out, woutt, 1024, 1024);

    // 1) qkv = x @ w_qkv   (768 blocks, %8==0 -> bijective XCD swizzle)
    gemm256<unsigned short><<<(3072 / 256) * (MROWS / 256), 512, 131072, stream>>>(
        xb, wqkvt, qkv, MROWS, 3072, DD);

    // 2) packed FFT -> P + chunk totals
    hrr_phaseA<<<BB * HH * NCHUNK, 256, 0, stream>>>(qkv, P, totals);

    // 3) exclusive scan of chunk totals
    hrr_phaseB<<<BB * HH, 256, 0, stream>>>(totals);

    // 4) scan P in-chunk + paired unbind + IFFT -> vals
    hrr_phaseC<<<BB * HH * NCHUNK, 256, 0, stream>>>(qkv, P, totals, vals);

    // 5) out = vals @ w_out  (256 blocks)
    gemm256<float><<<(DD / 256) * (MROWS / 256), 512, 131072, stream>>>(
        vals, woutt, out, MROWS, DD, DD);
}

// Round 4
// 369.042 us; speedup vs baseline: 1.0138x; 1.0138x over previous
//
#include <hip/hip_runtime.h>

// Problem constants
static constexpr int BB = 4;
static constexpr int SS = 4096;
static constexpr int DD = 1024;
static constexpr int HH = 8;
static constexpr int HD = 128;     // FFT length
static constexpr int CS = 32;      // scan chunk size (positions per block)
static constexpr int NCHUNK = SS / CS;   // 128
static constexpr int MROWS = BB * SS;    // 16384

typedef __attribute__((ext_vector_type(8))) short bfrag;    // 8 bf16 (4 VGPRs)
typedef __attribute__((ext_vector_type(4))) float floatx4;  // MFMA acc

// ---------------------------------------------------------------------------
// bf16 helpers
// ---------------------------------------------------------------------------
__device__ __forceinline__ float bf2f(unsigned int u) {   // low 16 bits = bf16
    return __uint_as_float((u & 0xFFFFu) << 16);
}
__device__ __forceinline__ unsigned short f2bf(float f) {  // RNE
    unsigned int x = __float_as_uint(f);
    unsigned int r = x + 0x7FFFu + ((x >> 16) & 1u);
    return (unsigned short)(r >> 16);
}
__device__ __forceinline__ unsigned int pack_rne(float a, float b) {
    return ((unsigned int)f2bf(a)) | (((unsigned int)f2bf(b)) << 16);
}

// async global->LDS, 16B per lane; LDS dest = wave-uniform base + lane*16
__device__ __forceinline__ void async_copy16(const void* g, void* l) {
    __builtin_amdgcn_global_load_lds(
        (const __attribute__((address_space(1))) unsigned int*)g,
        (__attribute__((address_space(3))) unsigned int*)l, 16, 0, 0);
}

// ---------------------------------------------------------------------------
// Complex helpers
// ---------------------------------------------------------------------------
struct cpx { float re, im; };

__device__ __forceinline__ cpx cadd(cpx a, cpx b) { return {a.re + b.re, a.im + b.im}; }
__device__ __forceinline__ cpx csub(cpx a, cpx b) { return {a.re - b.re, a.im - b.im}; }
__device__ __forceinline__ cpx cmul(cpx a, cpx b) {
    return { fmaf(a.re, b.re, -a.im * b.im), fmaf(a.re, b.im, a.im * b.re) };
}
__device__ __forceinline__ cpx cmul_cj(cpx a, cpx b) {   // a * conj(b)
    return { fmaf(a.re, b.re, a.im * b.im), fmaf(a.im, b.re, -a.re * b.im) };
}
__device__ __forceinline__ cpx shflx(cpx x, int m) {
    return { __shfl_xor(x.re, m), __shfl_xor(x.im, m) };
}
__device__ __forceinline__ cpx shfl_at(cpx x, int src) {
    return { __shfl(x.re, src), __shfl(x.im, src) };
}

__device__ __forceinline__ int pair_lane_even(int l) {
    int m = (int)(__brev((unsigned)l) >> 26);
    int mp = (64 - m) & 63;
    return (int)(__brev((unsigned)mp) >> 26);
}

__device__ __forceinline__ void make_tw(int lane, cpx tw[7]) {
    const float NEG2PI = -6.28318530717958647692f;
    float a0 = NEG2PI * (float)lane * (1.0f / 128.0f);
    tw[0] = { __cosf(a0), __sinf(a0) };
    int d = 32;
#pragma unroll
    for (int s = 1; s <= 6; ++s) {
        int i = lane & (d - 1);
        float a = NEG2PI * (float)i / (float)(2 * d);
        tw[s] = { __cosf(a), __sinf(a) };
        d >>= 1;
    }
}

// Forward DIF FFT-128 (complex): natural in, bit-reversed out. Unnormalized.
__device__ __forceinline__ void fft128_fwd(cpx& x0, cpx& x1, const cpx tw[7], int lane) {
    cpx a = x0, b = x1;
    x0 = cadd(a, b);
    x1 = cmul(csub(a, b), tw[0]);
    int d = 32;
#pragma unroll
    for (int s = 1; s <= 6; ++s) {
        const bool up = (lane & d) != 0;
        cpx o0 = shflx(x0, d);
        cpx o1 = shflx(x1, d);
        cpx s0 = cadd(x0, o0);
        cpx s1 = cadd(x1, o1);
        cpx d0 = cmul(csub(o0, x0), tw[s]);
        cpx d1 = cmul(csub(o1, x1), tw[s]);
        x0 = up ? d0 : s0;
        x1 = up ? d1 : s1;
        d >>= 1;
    }
}

// Inverse DIT FFT-128: consumes fwd's permuted order, natural order out, /128.
__device__ __forceinline__ void fft128_inv(cpx& x0, cpx& x1, const cpx tw[7], int lane) {
    int d = 1;
#pragma unroll
    for (int s = 6; s >= 1; --s) {
        const bool up = (lane & d) != 0;
        cpx o0 = shflx(x0, d);
        cpx o1 = shflx(x1, d);
        cpx b0 = up ? x0 : o0;
        cpx a0 = up ? o0 : x0;
        cpx b1 = up ? x1 : o1;
        cpx a1 = up ? o1 : x1;
        cpx t0 = cmul_cj(b0, tw[s]);
        cpx t1 = cmul_cj(b1, tw[s]);
        x0 = up ? csub(a0, t0) : cadd(a0, t0);
        x1 = up ? csub(a1, t1) : cadd(a1, t1);
        d <<= 1;
    }
    cpx t = cmul_cj(x1, tw[0]);
    cpx a = x0;
    const float inv = 0.0078125f;
    x0 = { (a.re + t.re) * inv, (a.im + t.im) * inv };
    x1 = { (a.re - t.re) * inv, (a.im - t.im) * inv };
}

// ---------------------------------------------------------------------------
// x fp32 -> bf16 (RNE), 8 elems/thread
// ---------------------------------------------------------------------------
__global__ __launch_bounds__(256) void convert_bf16(const float* __restrict__ X,
                                                    unsigned short* __restrict__ Y)
{
    const size_t i = ((size_t)blockIdx.x * 256 + threadIdx.x) * 8;
    float4 v0 = *reinterpret_cast<const float4*>(X + i);
    float4 v1 = *reinterpret_cast<const float4*>(X + i + 4);
    uint4 p = { pack_rne(v0.x, v0.y), pack_rne(v0.z, v0.w),
                pack_rne(v1.x, v1.y), pack_rne(v1.z, v1.w) };
    *reinterpret_cast<uint4*>(Y + i) = p;
}

// Transpose + RNE bf16: W fp32 [K,N] -> T bf16 [N,K]
__global__ __launch_bounds__(256) void transpose_rn(const float* __restrict__ W,
                                                    unsigned short* __restrict__ T,
                                                    int K, int N)
{
    __shared__ float tile[32][33];
    const int n0 = blockIdx.x * 32, k0 = blockIdx.y * 32;
    const int r = threadIdx.x >> 5, c = threadIdx.x & 31;
#pragma unroll
    for (int i = 0; i < 4; ++i)
        tile[r + 8 * i][c] = W[(size_t)(k0 + r + 8 * i) * N + n0 + c];
    __syncthreads();
#pragma unroll
    for (int i = 0; i < 4; ++i) {
        float v = tile[c][r + 8 * i];
        T[(size_t)(n0 + r + 8 * i) * K + k0 + c] = f2bf(v);
    }
}

// ---------------------------------------------------------------------------
// 256x256-tile bf16 GEMM, BK=64, 4 phases/iter (R2 skeleton), NO scheduling
// pins: no sched_barrier(0), no blanket lgkmcnt(0).  MFMA operands are
// intrinsic-level ds_read results, so the compiler emits operand-exact
// lgkmcnt(N) waits -> early MFMAs issue while later reads drain (m97/m141
// evidence: order-pinning costs ~40%).  Counted vmcnt (never 0 in steady
// state).  C[M,N] = A[M,K](bf16) * Bt[N,K]^T(bf16).
//
// LDS 128 KiB = 2 bufs x { A[kk][256][32] | B[kk][256][32] } (4x16KB halves).
//
// Phase map (iter i):  q0: MFMA af0 x bf0 (kk0, m0-3); stage B1(i+1)
//                      q1: MFMA af1 x bf0 (kk0, m4-7); stage A1(i+1); vmcnt(6)
//                      q2: MFMA af0 x bf1 (kk1, m0-3); stage B0(i+2)
//                      q3: MFMA af1 x bf1 (kk1, m4-7); stage A0(i+2); vmcnt(6)
// Slot lifetimes (unchanged from R2): every stage is issued >=1 barrier AFTER
// the slot's last read; every staged half-tile has >=5 phases to land; the
// vmcnt(6) (3 half-tiles x 2 loads/wave in flight) at q1/q3 publishes landing
// through the following barrier.  Tail iters tighten the immediates.
//
// Swizzle (both-sides, rule #21): LDS 16B-slot s of row r holds global slot
// s ^ ((r>>1)&3); applied by pre-swizzling the per-lane GLOBAL source (LDS
// dest stays linear for global_load_lds) and XOR-ing the ds_read address.
// ---------------------------------------------------------------------------
template <typename OutT>
__global__ __launch_bounds__(512, 2) void gemm256(const unsigned short* __restrict__ A,
                                                  const unsigned short* __restrict__ Bt,
                                                  OutT* __restrict__ C,
                                                  int M, int N, int K)
{
    extern __shared__ __align__(16) unsigned short lds[];

    const int tid = threadIdx.x, lane = tid & 63, w = tid >> 6;
    const int wr = w >> 2, wc = w & 3;   // 2 x 4 wave grid, per-wave out 128x64

    // T1: XCD-aware bijective swizzle (gridDim.x % 8 == 0 here)
    const int nbx = N >> 8;
    const int cpx_ = gridDim.x >> 3;
    const int wg = blockIdx.x;
    const int swz = (wg & 7) * cpx_ + (wg >> 3);
    const int n0 = (swz % nbx) << 8;
    const int m0 = (swz / nbx) << 8;

    // --- staging (per-lane global source carries the inverse swizzle) ---
    const int lr = lane >> 2;                                  // row within 16-row chunk
    const int kx = (((lane & 3) ^ ((lane >> 3) & 3)) << 3);    // swizzled k-elem offset
    const unsigned short* gA = A  + (size_t)(m0 + 32 * w + lr) * K + kx;
    const unsigned short* gB = Bt + (size_t)(n0 + 32 * w + lr) * K + kx;

    auto stageA = [&](int buf, int kk, int kelem) {
        unsigned short* dst = lds + buf * 32768 + kk * 8192 + (32 * w) * 32;
        const unsigned short* src = gA + kelem;
        async_copy16(src, dst);
        async_copy16(src + (size_t)16 * K, dst + 512);
    };
    auto stageB = [&](int buf, int kk, int kelem) {
        unsigned short* dst = lds + buf * 32768 + 16384 + kk * 8192 + (32 * w) * 32;
        const unsigned short* src = gB + kelem;
        async_copy16(src, dst);
        async_copy16(src + (size_t)16 * K, dst + 512);
    };

    // --- fragment read bases (ushort units) ---
    const int sl = lane >> 4;                        // global 16B k-slot wanted
    const int xa = ((lane & 15) >> 1) & 3;           // row-derived XOR
    const int soff = ((sl ^ xa) << 3);
    const int ra = (wr * 128 + (lane & 15)) * 32 + soff;   // + m*512
    const int rb = (wc * 64  + (lane & 15)) * 32 + soff;   // + n*512

    floatx4 acc[8][4];
#pragma unroll
    for (int m = 0; m < 8; ++m)
#pragma unroll
        for (int n = 0; n < 4; ++n) { floatx4 z = {0.f, 0.f, 0.f, 0.f}; acc[m][n] = z; }

    const int NT = K >> 6;   // BK = 64 per iter (NT = 16 here)

    // prologue: iter0 all 4 halves + iter1 kk0 pair
    stageA(0, 0, 0);  stageB(0, 0, 0);
    stageA(0, 1, 32); stageB(0, 1, 32);
    if (NT > 1) { stageA(1, 0, 64); stageB(1, 0, 64); }
    asm volatile("s_waitcnt vmcnt(8)" ::: "memory");   // A0(0), B0(0) landed
    __builtin_amdgcn_s_barrier();

    for (int i = 0; i < NT; ++i) {
        const int bb = (i & 1) * 32768;
        bfrag af0[4], af1[4], bf0[4], bf1[4];

        // ---- q0: kk0, m0-3 x n0-3; stage B1(i+1) ----
        {
            const unsigned short* pA = lds + bb + ra;
            const unsigned short* pB = lds + bb + 16384 + rb;
#pragma unroll
            for (int m = 0; m < 4; ++m) af0[m] = *reinterpret_cast<const bfrag*>(pA + m * 512);
#pragma unroll
            for (int n = 0; n < 4; ++n) bf0[n] = *reinterpret_cast<const bfrag*>(pB + n * 512);
            if (i + 1 < NT) stageB((i + 1) & 1, 1, (i + 1) * 64 + 32);
            __builtin_amdgcn_s_barrier();
            __builtin_amdgcn_s_setprio(1);
#pragma unroll
            for (int m = 0; m < 4; ++m)
#pragma unroll
                for (int n = 0; n < 4; ++n)
                    acc[m][n] = __builtin_amdgcn_mfma_f32_16x16x32_bf16(af0[m], bf0[n], acc[m][n], 0, 0, 0);
            __builtin_amdgcn_s_setprio(0);
            __builtin_amdgcn_s_barrier();
        }

        // ---- q1: kk0, m4-7 x n0-3 (bf0 reg-reuse); stage A1(i+1); vmcnt ----
        {
            const unsigned short* pA = lds + bb + ra + 2048;
#pragma unroll
            for (int m = 0; m < 4; ++m) af1[m] = *reinterpret_cast<const bfrag*>(pA + m * 512);
            if (i + 1 < NT) {
                stageA((i + 1) & 1, 1, (i + 1) * 64 + 32);
                asm volatile("s_waitcnt vmcnt(6)" ::: "memory");
            } else {
                asm volatile("s_waitcnt vmcnt(0)" ::: "memory");
            }
            __builtin_amdgcn_s_barrier();
            __builtin_amdgcn_s_setprio(1);
#pragma unroll
            for (int m = 0; m < 4; ++m)
#pragma unroll
                for (int n = 0; n < 4; ++n)
                    acc[4 + m][n] = __builtin_amdgcn_mfma_f32_16x16x32_bf16(af1[m], bf0[n], acc[4 + m][n], 0, 0, 0);
            __builtin_amdgcn_s_setprio(0);
            __builtin_amdgcn_s_barrier();
        }

        // ---- q2: kk1, m0-3 x n0-3; stage B0(i+2) ----
        {
            const unsigned short* pA = lds + bb + 8192 + ra;
            const unsigned short* pB = lds + bb + 16384 + 8192 + rb;
#pragma unroll
            for (int m = 0; m < 4; ++m) af0[m] = *reinterpret_cast<const bfrag*>(pA + m * 512);
#pragma unroll
            for (int n = 0; n < 4; ++n) bf1[n] = *reinterpret_cast<const bfrag*>(pB + n * 512);
            if (i + 2 < NT) stageB(i & 1, 0, (i + 2) * 64);
            __builtin_amdgcn_s_barrier();
            __builtin_amdgcn_s_setprio(1);
#pragma unroll
            for (int m = 0; m < 4; ++m)
#pragma unroll
                for (int n = 0; n < 4; ++n)
                    acc[m][n] = __builtin_amdgcn_mfma_f32_16x16x32_bf16(af0[m], bf1[n], acc[m][n], 0, 0, 0);
            __builtin_amdgcn_s_setprio(0);
            __builtin_amdgcn_s_barrier();
        }

        // ---- q3: kk1, m4-7 x n0-3 (bf1 reg-reuse); stage A0(i+2); vmcnt ----
        {
            const unsigned short* pA = lds + bb + 8192 + ra + 2048;
#pragma unroll
            for (int m = 0; m < 4; ++m) af1[m] = *reinterpret_cast<const bfrag*>(pA + m * 512);
            if (i + 2 < NT) {
                stageA(i & 1, 0, (i + 2) * 64);
                asm volatile("s_waitcnt vmcnt(6)" ::: "memory");
            } else if (i + 1 < NT) {
                asm volatile("s_waitcnt vmcnt(2)" ::: "memory");
            } else {
                asm volatile("s_waitcnt vmcnt(0)" ::: "memory");
            }
            __builtin_amdgcn_s_barrier();
            __builtin_amdgcn_s_setprio(1);
#pragma unroll
            for (int m = 0; m < 4; ++m)
#pragma unroll
                for (int n = 0; n < 4; ++n)
                    acc[4 + m][n] = __builtin_amdgcn_mfma_f32_16x16x32_bf16(af1[m], bf1[n], acc[4 + m][n], 0, 0, 0);
            __builtin_amdgcn_s_setprio(0);
            __builtin_amdgcn_s_barrier();
        }
    }

    // ---- epilogue ----
    if constexpr (sizeof(OutT) == 2) {
        // repack through LDS (all waves past final barrier): wave-private
        // 128x64 bf16 tile, then 16B/lane coalesced stores.
        unsigned short* myt = lds + w * 8192;
#pragma unroll
        for (int m = 0; m < 8; ++m)
#pragma unroll
            for (int n = 0; n < 4; ++n)
#pragma unroll
                for (int r = 0; r < 4; ++r)
                    myt[(m * 16 + sl * 4 + r) * 64 + n * 16 + (lane & 15)] = f2bf(acc[m][n][r]);
        asm volatile("s_waitcnt lgkmcnt(0)" ::: "memory");
#pragma unroll
        for (int c = 0; c < 16; ++c) {
            const int idx = c * 64 + lane;
            const int row = idx >> 3, cc = (idx & 7) << 3;
            uint4 v = *reinterpret_cast<const uint4*>(myt + idx * 8);
            *reinterpret_cast<uint4*>(C + (size_t)(m0 + wr * 128 + row) * N + (n0 + wc * 64 + cc)) = v;
        }
    } else {
        // fp32: repack through LDS in two 64-row passes (wave-private 16 KB),
        // then 16B/lane coalesced float4 stores.
        float* myf = reinterpret_cast<float*>(lds) + w * 4096;
#pragma unroll
        for (int pass = 0; pass < 2; ++pass) {
#pragma unroll
            for (int mp = 0; mp < 4; ++mp) {
                const int m = pass * 4 + mp;
#pragma unroll
                for (int n = 0; n < 4; ++n)
#pragma unroll
                    for (int r = 0; r < 4; ++r)
                        myf[(mp * 16 + sl * 4 + r) * 64 + n * 16 + (lane & 15)] = acc[m][n][r];
            }
            asm volatile("s_waitcnt lgkmcnt(0)" ::: "memory");
#pragma unroll
            for (int c = 0; c < 16; ++c) {
                const int idx = c * 64 + lane;       // 0..1023
                const int row = idx >> 4;            // 0..63
                const int cc = (idx & 15) << 2;      // 0..60
                float4 v = *reinterpret_cast<const float4*>(myf + row * 64 + cc);
                *reinterpret_cast<float4*>(
                    C + (size_t)(m0 + wr * 128 + pass * 64 + row) * N + (n0 + wc * 64 + cc)) = v;
            }
            asm volatile("s_waitcnt lgkmcnt(0)" ::: "memory");
        }
    }
}

// ---------------------------------------------------------------------------
// Phase A: one packed FFT Z=FFT(k+iv) per position; P = FK*FV via conjugate
// pairing. Stores P (bf16 packed, permuted array-position order) and
// per-chunk totals (fp32).
// ---------------------------------------------------------------------------
__global__ __launch_bounds__(256) void hrr_phaseA(const unsigned short* __restrict__ qkv,
                                                  unsigned int* __restrict__ P,
                                                  float* __restrict__ totals)
{
    const int blk = blockIdx.x;
    const int bh = blk / NCHUNK;
    const int chunk = blk % NCHUNK;
    const int b = bh >> 3, h = bh & 7;
    const int tid = threadIdx.x;
    const int wave = tid >> 6, lane = tid & 63;

    cpx tw[7];
    make_tw(lane, tw);
    const int pl0 = pair_lane_even(lane);
    const int pl1 = lane ^ 63;

    cpx acc0 = {0.f, 0.f}, acc1 = {0.f, 0.f};
    const int s0 = chunk * CS + wave * (CS / 4);
    for (int i = 0; i < CS / 4; ++i) {
        const int s = s0 + i;
        const unsigned short* base = qkv + (size_t)(b * SS + s) * 3072 + h * 128;
        cpx z0 = { bf2f(base[1024 + lane]),      bf2f(base[2048 + lane]) };
        cpx z1 = { bf2f(base[1024 + 64 + lane]), bf2f(base[2048 + 64 + lane]) };
        fft128_fwd(z0, z1, tw, lane);
        cpx sq0 = cmul(z0, z0);
        cpx sq1 = cmul(z1, z1);
        cpx sp0 = shfl_at(sq0, pl0);
        cpx sp1 = shfl_at(sq1, pl1);
        cpx p0 = { 0.25f * (sq0.im + sp0.im), 0.25f * (sp0.re - sq0.re) };
        cpx p1 = { 0.25f * (sq1.im + sp1.im), 0.25f * (sp1.re - sq1.re) };
        acc0 = cadd(acc0, p0);
        acc1 = cadd(acc1, p1);
        unsigned int* prow = P + ((size_t)bh * SS + s) * 128;
        prow[lane]      = pack_rne(p0.re, p0.im);
        prow[64 + lane] = pack_rne(p1.re, p1.im);
    }

    __shared__ float red[4][256];
    red[wave][lane * 2 + 0] = acc0.re;
    red[wave][lane * 2 + 1] = acc0.im;
    red[wave][128 + lane * 2 + 0] = acc1.re;
    red[wave][128 + lane * 2 + 1] = acc1.im;
    __syncthreads();

    float s4 = red[0][tid] + red[1][tid] + red[2][tid] + red[3][tid];
    totals[((size_t)bh * NCHUNK + chunk) * 256 + tid] = s4;
}

// ---------------------------------------------------------------------------
// Phase B: exclusive scan of chunk totals over 128 chunks per (bh, comp)
// ---------------------------------------------------------------------------
__global__ __launch_bounds__(256) void hrr_phaseB(float* __restrict__ totals)
{
    const int bh = blockIdx.x;
    const int t = threadIdx.x;
    float run = 0.f;
#pragma unroll 4
    for (int c = 0; c < NCHUNK; ++c) {
        const size_t idx = ((size_t)bh * NCHUNK + c) * 256 + t;
        float v = totals[idx];
        totals[idx] = run;
        run += v;
    }
}

// ---------------------------------------------------------------------------
// Phase C: load P (bf16) -> fp32 LDS, in-chunk scan, then paired unbind + IFFT
// ---------------------------------------------------------------------------
__global__ __launch_bounds__(256) void hrr_phaseC(const unsigned short* __restrict__ qkv,
                                                  const unsigned int* __restrict__ P,
                                                  const float* __restrict__ totals,
                                                  unsigned short* __restrict__ vals)
{
    __shared__ float Pf[CS * 256];   // 32 KB

    const int blk = blockIdx.x;
    const int bh = blk / NCHUNK;
    const int chunk = blk % NCHUNK;
    const int b = bh >> 3, h = bh & 7;
    const int tid = threadIdx.x;
    const int wave = tid >> 6, lane = tid & 63;

    cpx tw[7];
    make_tw(lane, tw);
    const int pl0 = pair_lane_even(lane);
    const int pl1 = lane ^ 63;

#pragma unroll
    for (int it = 0; it < CS / 4; ++it) {
        const int sl = it * 4 + wave;
        const int s = chunk * CS + sl;
        const unsigned int* prow = P + ((size_t)bh * SS + s) * 128;
        unsigned int a = prow[lane];
        unsigned int c = prow[64 + lane];
        float2 fa = { bf2f(a), bf2f(a >> 16) };
        float2 fc = { bf2f(c), bf2f(c >> 16) };
        *reinterpret_cast<float2*>(&Pf[sl * 256 + 2 * lane]) = fa;
        *reinterpret_cast<float2*>(&Pf[sl * 256 + 128 + 2 * lane]) = fc;
    }
    __syncthreads();

    {
        float run = totals[((size_t)bh * NCHUNK + chunk) * 256 + tid];
#pragma unroll 8
        for (int s = 0; s < CS; ++s) {
            run += Pf[s * 256 + tid];
            Pf[s * 256 + tid] = run;
        }
    }
    __syncthreads();

    for (int i = 0; i < CS / 8; ++i) {
        const int sl = wave * (CS / 4) + 2 * i;
        const int s1 = chunk * CS + sl;
        const unsigned short* b1 = qkv + (size_t)(b * SS + s1) * 3072 + h * 128;
        const unsigned short* b2 = b1 + 3072;
        cpx z0 = { bf2f(b1[lane]),      bf2f(b2[lane]) };
        cpx z1 = { bf2f(b1[64 + lane]), bf2f(b2[64 + lane]) };
        fft128_fwd(z0, z1, tw, lane);
        cpx B0 = shfl_at(z0, pl0);
        cpx B1 = shfl_at(z1, pl1);
        cpx cf1_0 = { 0.5f * (z0.re + B0.re), 0.5f * (B0.im - z0.im) };
        cpx cf1_1 = { 0.5f * (z1.re + B1.re), 0.5f * (B1.im - z1.im) };
        cpx cf2_0 = { 0.5f * (z0.im + B0.im), 0.5f * (z0.re - B0.re) };
        cpx cf2_1 = { 0.5f * (z1.im + B1.im), 0.5f * (z1.re - B1.re) };

        const float* r1 = &Pf[sl * 256];
        const float* r2 = r1 + 256;
        float2 t0 = *reinterpret_cast<const float2*>(&r1[2 * lane]);
        float2 t1 = *reinterpret_cast<const float2*>(&r1[128 + 2 * lane]);
        float2 t2 = *reinterpret_cast<const float2*>(&r2[2 * lane]);
        float2 t3 = *reinterpret_cast<const float2*>(&r2[128 + 2 * lane]);
        cpx C1_0 = { t0.x, t0.y }, C1_1 = { t1.x, t1.y };
        cpx C2_0 = { t2.x, t2.y }, C2_1 = { t3.x, t3.y };

        cpx a0 = cmul(C1_0, cf1_0), w0 = cmul(C2_0, cf2_0);
        cpx a1 = cmul(C1_1, cf1_1), w1 = cmul(C2_1, cf2_1);
        cpx u0 = { a0.re - w0.im, a0.im + w0.re };
        cpx u1 = { a1.re - w1.im, a1.im + w1.re };
        fft128_inv(u0, u1, tw, lane);

        unsigned short* o1 = vals + (size_t)(b * SS + s1) * DD + h * 128;
        unsigned short* o2 = o1 + DD;
        o1[lane]      = f2bf(u0.re);
        o1[64 + lane] = f2bf(u1.re);
        o2[lane]      = f2bf(u0.im);
        o2[64 + lane] = f2bf(u1.im);
    }
}

// ---------------------------------------------------------------------------
// Launch
// ---------------------------------------------------------------------------
extern "C" void kernel_launch(void* const* d_in, const int* in_sizes, int n_in,
                              void* d_out, int out_size, void* d_ws, size_t ws_size,
                              hipStream_t stream) {
    const float* x     = (const float*)d_in[0];   // [B,S,D]
    const float* w_qkv = (const float*)d_in[1];   // [D, 3D]
    const float* w_out = (const float*)d_in[2];   // [D, D]
    float* out = (float*)d_out;                   // [B,S,D]

    unsigned short* qkv  = (unsigned short*)d_ws;
    unsigned short* xb   = qkv + (size_t)MROWS * 3072;
    unsigned short* vals = xb + (size_t)MROWS * DD;
    unsigned int* P      = (unsigned int*)(vals + (size_t)MROWS * DD);
    float* totals        = (float*)(P + (size_t)32 * SS * 128);
    unsigned short* wqkvt = (unsigned short*)(totals + (size_t)32 * NCHUNK * 256);
    unsigned short* woutt = wqkvt + (size_t)3072 * 1024;

    // allow 128 KiB dynamic LDS (idempotent; not a stream op)
    static bool attr_done = false;
    if (!attr_done) {
        hipFuncSetAttribute(reinterpret_cast<const void*>(gemm256<unsigned short>),
                            hipFuncAttributeMaxDynamicSharedMemorySize, 131072);
        hipFuncSetAttribute(reinterpret_cast<const void*>(gemm256<float>),
                            hipFuncAttributeMaxDynamicSharedMemorySize, 131072);
        attr_done = true;
    }

    // 0) input prep
    convert_bf16<<<(MROWS * DD) / (256 * 8), 256, 0, stream>>>(x, xb);
    transpose_rn<<<dim3(3072 / 32, 1024 / 32), 256, 0, stream>>>(w_qkv, wqkvt, 1024, 3072);
    transpose_rn<<<dim3(1024 / 32, 1024 / 32), 256, 0, stream>>>(w_out, woutt, 1024, 1024);

    // 1) qkv = x @ w_qkv   (768 blocks, %8==0 -> bijective XCD swizzle)
    gemm256<unsigned short><<<(3072 / 256) * (MROWS / 256), 512, 131072, stream>>>(
        xb, wqkvt, qkv, MROWS, 3072, DD);

    // 2) packed FFT -> P + chunk totals
    hrr_phaseA<<<BB * HH * NCHUNK, 256, 0, stream>>>(qkv, P, totals);

    // 3) exclusive scan of chunk totals
    hrr_phaseB<<<BB * HH, 256, 0, stream>>>(totals);

    // 4) scan P in-chunk + paired unbind + IFFT -> vals
    hrr_phaseC<<<BB * HH * NCHUNK, 256, 0, stream>>>(qkv, P, totals, vals);

    // 5) out = vals @ w_out  (256 blocks)
    gemm256<float><<<(DD / 256) * (MROWS / 256), 512, 131072, stream>>>(
        vals, woutt, out, MROWS, DD, DD);
}